// Round 9
// baseline (46.505 us; speedup 1.0000x reference)
//
#include <hip/hip_runtime.h>
#include <math.h>

#define BB 4
#define TT 4096
#define CC 1024
#define HH 64
#define MM (BB*TT)

typedef __attribute__((ext_vector_type(8))) short  short8;
typedef __attribute__((ext_vector_type(4))) short  short4v;
typedef __attribute__((ext_vector_type(4))) float  f32x4;

typedef const __attribute__((address_space(1))) unsigned int GU;
typedef __attribute__((address_space(3))) unsigned int LU;

static __device__ __forceinline__ unsigned short f2bf(float f) {
    union { float f; unsigned u; } v; v.f = f;
    unsigned r = v.u + 0x7FFF + ((v.u >> 16) & 1);
    return (unsigned short)(r >> 16);
}

// 8x fp32 -> 8x bf16 (RNE) via v_cvt_pk_bf16_f32 (2 floats/instr)
static __device__ __forceinline__ short8 cvt8(float4 lo, float4 hi) {
    unsigned u0, u1, u2, u3;
    asm("v_cvt_pk_bf16_f32 %0, %1, %2" : "=v"(u0) : "v"(lo.x), "v"(lo.y));
    asm("v_cvt_pk_bf16_f32 %0, %1, %2" : "=v"(u1) : "v"(lo.z), "v"(lo.w));
    asm("v_cvt_pk_bf16_f32 %0, %1, %2" : "=v"(u2) : "v"(hi.x), "v"(hi.y));
    asm("v_cvt_pk_bf16_f32 %0, %1, %2" : "=v"(u3) : "v"(hi.z), "v"(hi.w));
    union { unsigned u[4]; short8 s; } r;
    r.u[0] = u0; r.u[1] = u1; r.u[2] = u2; r.u[3] = u3;
    return r.s;
}

// ---------------- Kernel 0: W -> W^T bf16 (tiny, unchanged) ----------------
__global__ __launch_bounds__(256) void convw_kernel(
        const float* __restrict__ Wq, const float* __restrict__ Wk,
        const float* __restrict__ Wv, unsigned short* __restrict__ wtb) {
    __shared__ unsigned short sW[64][66];
    const int m    = blockIdx.x >> 4;
    const int cblk = blockIdx.x & 15;
    const float* W = (m == 0) ? Wq : (m == 1) ? Wk : Wv;
    const int lane = threadIdx.x & 63;
    const int w    = threadIdx.x >> 6;
    #pragma unroll
    for (int rep = 0; rep < 16; ++rep) {
        const int cl = w * 16 + rep;
        sW[cl][lane] = f2bf(W[(size_t)(cblk * 64 + cl) * HH + lane]);
    }
    __syncthreads();
    #pragma unroll
    for (int rep = 0; rep < 16; ++rep) {
        const int h2 = w * 16 + rep;
        wtb[(size_t)(m * 64 + h2) * CC + cblk * 64 + lane] = sW[lane][h2];
    }
}

// ---------------- Kernel 1: decoupled-wait MFMA projection ----------------
// Swapped operands: A = W (direct L2-hot reg loads, depth-1 prefetch),
// B = x (4-deep LDS DMA ring, staged 3 iters ahead, wait = vmcnt(2) only).
// BM=32 rows/block, BN=192 = 4 waves x 48 cols. grid = 512. One s_barrier/iter.
__global__ __launch_bounds__(256, 3) void gemm_kernel(
        const float* __restrict__ x,
        const unsigned short* __restrict__ wtb,
        unsigned short* __restrict__ qb,
        unsigned short* __restrict__ kb,
        unsigned short* __restrict__ vt) {
    __shared__ char  Asb[4 * 8192];     // 4-deep ring: 32 rows x 64 k fp32, swizzled
    __shared__ float vstage[64][33];    // v epilogue transpose

    const int tid  = threadIdx.x;
    const int lane = tid & 63;
    const int w    = tid >> 6;
    const int l15  = lane & 15;
    const int lg   = lane >> 4;
    const int row0 = blockIdx.x * 32;
    const int wc   = w * 48;

    // A(x)-DMA source: slot-XOR swizzle folded into global address (r7-verified)
    const int arow  = tid >> 4;
    const int aslot = (tid & 15) ^ arow;
    const float* asrc0 = x + (size_t)(row0 + arow) * CC + aslot * 4;
    const float* asrc1 = x + (size_t)(row0 + 16 + arow) * CC + aslot * 4;

    // W rows (bf16, L2-hot): n = wc + nf*16 + l15, k-base lg*8
    const unsigned short* wp0 = wtb + (size_t)(wc +  0 + l15) * CC + lg * 8;
    const unsigned short* wp1 = wtb + (size_t)(wc + 16 + l15) * CC + lg * 8;
    const unsigned short* wp2 = wtb + (size_t)(wc + 32 + l15) * CC + lg * 8;

    f32x4 acc[3][2];   // [nf][mf]: rows n = wc+nf*16+lg*4+r, cols m = row0+mf*16+l15
    #pragma unroll
    for (int i = 0; i < 3; ++i)
        #pragma unroll
        for (int j = 0; j < 2; ++j)
            acc[i][j] = (f32x4){0.f, 0.f, 0.f, 0.f};

    short8 breg[2][3][2];   // double-buffered W fragments

#define STAGE_A(s_) { \
    const int kcs_ = ((s_) < 16 ? (s_) : 15) * 64; \
    __builtin_amdgcn_global_load_lds((GU*)(asrc0 + kcs_), \
        (LU*)(Asb + ((s_) & 3) * 8192 + w * 1024), 16, 0, 0); \
    __builtin_amdgcn_global_load_lds((GU*)(asrc1 + kcs_), \
        (LU*)(Asb + ((s_) & 3) * 8192 + 4096 + w * 1024), 16, 0, 0); }

#define LOAD_B(s_) { \
    const int kcs_ = ((s_) < 16 ? (s_) : 15) * 64; \
    breg[(s_) & 1][0][0] = *(const short8*)(wp0 + kcs_); \
    breg[(s_) & 1][0][1] = *(const short8*)(wp0 + kcs_ + 32); \
    breg[(s_) & 1][1][0] = *(const short8*)(wp1 + kcs_); \
    breg[(s_) & 1][1][1] = *(const short8*)(wp1 + kcs_ + 32); \
    breg[(s_) & 1][2][0] = *(const short8*)(wp2 + kcs_); \
    breg[(s_) & 1][2][1] = *(const short8*)(wp2 + kcs_ + 32); }

    // Pin VMEM issue order (FIFO vmcnt counting depends on it):
    // everything except VMEM may cross.
#define VMEM_FENCE() __builtin_amdgcn_sched_barrier(0x38F)

    // ---- prologue: B(0) first (oldest in FIFO), then A(0..2) ----
    LOAD_B(0);
    VMEM_FENCE();
    STAGE_A(0); STAGE_A(1); STAGE_A(2);
    VMEM_FENCE();

    #pragma unroll
    for (int t = 0; t < 16; ++t) {
        // steady state: drain through B(t) [+A(t+1)], leave newest A-DMA in flight
        if (t == 0) { asm volatile("s_waitcnt vmcnt(4)" ::: "memory"); }
        else        { asm volatile("s_waitcnt vmcnt(2)" ::: "memory"); }
        __builtin_amdgcn_sched_barrier(0);
        __builtin_amdgcn_s_barrier();
        __builtin_amdgcn_sched_barrier(0);

        LOAD_B(t + 1);     // L2-hot W for next iter (issued BEFORE the deep DMA)
        VMEM_FENCE();
        STAGE_A(t + 3);    // HBM x stream, 3 iterations ahead
        VMEM_FENCE();

        // x fragments from ring buffer (t&3): swizzled fp32 read + cvt
        const char* Ab = Asb + (t & 3) * 8192;
        short8 xf[2][2];
        #pragma unroll
        for (int mf = 0; mf < 2; ++mf)
            #pragma unroll
            for (int kh = 0; kh < 2; ++kh) {
                const int row  = mf * 16 + l15;
                const int l16  = kh * 8 + lg * 2;
                const int pos0 = l16 ^ l15;
                float4 lo = *(const float4*)(Ab + row * 256 + pos0 * 16);
                float4 hi = *(const float4*)(Ab + row * 256 + (pos0 ^ 1) * 16);
                xf[mf][kh] = cvt8(lo, hi);
            }
        #pragma unroll
        for (int kh = 0; kh < 2; ++kh)
            #pragma unroll
            for (int nf = 0; nf < 3; ++nf)
                #pragma unroll
                for (int mf = 0; mf < 2; ++mf)
                    acc[nf][mf] = __builtin_amdgcn_mfma_f32_16x16x32_bf16(
                        breg[t & 1][nf][kh], xf[mf][kh], acc[nf][mf], 0, 0, 0);
    }

    // ---- epilogue ----
    const int b = row0 >> 12;
    #pragma unroll
    for (int nf = 0; nf < 3; ++nf) {
        const int ng = wc + nf * 16;
        #pragma unroll
        for (int mf = 0; mf < 2; ++mf) {
            const int m = row0 + mf * 16 + l15;          // global row
            if (ng < 128) {
                const int nb = ng + lg * 4;              // n-quad base
                unsigned short* dst = ((nb < 64) ? qb : kb) + (size_t)m * HH + (nb & 63);
                short4v o;
                o[0] = (short)f2bf(acc[nf][mf][0]);
                o[1] = (short)f2bf(acc[nf][mf][1]);
                o[2] = (short)f2bf(acc[nf][mf][2]);
                o[3] = (short)f2bf(acc[nf][mf][3]);
                *reinterpret_cast<short4v*>(dst) = o;
            } else {
                #pragma unroll
                for (int r = 0; r < 4; ++r)
                    vstage[ng - 128 + lg * 4 + r][mf * 16 + l15] = acc[nf][mf][r];
            }
        }
    }
    __syncthreads();
    #pragma unroll
    for (int it = 0; it < 2; ++it) {
        const int i  = tid + it * 256;
        const int h  = i >> 3, mq = i & 7;
        short4v o;
        #pragma unroll
        for (int r = 0; r < 4; ++r)
            o[r] = (short)f2bf(vstage[h][mq * 4 + r]);
        *reinterpret_cast<short4v*>(
            vt + ((size_t)(b * 64 + h)) * TT + (row0 & (TT - 1)) + mq * 4) = o;
    }
#undef STAGE_A
#undef LOAD_B
#undef VMEM_FENCE
}

// ---------------- Kernel 2: MFMA windowed causal attention ----------------
// (unchanged since round 4)
__global__ __launch_bounds__(256) void attn_kernel(
        const unsigned short* __restrict__ qb,
        const unsigned short* __restrict__ kb,
        const unsigned short* __restrict__ vt,
        const float* __restrict__ decay,
        float* __restrict__ out) {
    __shared__ unsigned short P[4][16 * 168];

    const int lane = threadIdx.x & 63;
    const int w    = threadIdx.x >> 6;
    const int l15  = lane & 15;
    const int lg   = lane >> 4;
    const int qt   = blockIdx.x * 4 + w;
    const int gb   = qt >> 8;
    const int i0   = (qt & 255) << 4;

    const float dec = fabsf(decay[0]);
    const size_t bbase = (size_t)gb * TT;

    short8 af0, af1;
    {
        const unsigned short* qp = qb + (bbase + i0 + l15) * HH + lg * 8;
        af0 = *(const short8*)(qp);
        af1 = *(const short8*)(qp + 32);
    }

    float psum[4] = {0.f, 0.f, 0.f, 0.f};
    unsigned short* Pw = &P[w][0];

    if (i0 >= 144) {
        const int js = i0 - 144;
        const unsigned short* kp = kb + (bbase + js + l15) * HH + lg * 8;
        #pragma unroll
        for (int ts = 0; ts < 10; ++ts) {
            short8 b0 = *(const short8*)(kp + (size_t)ts * 16 * HH);
            short8 b1 = *(const short8*)(kp + (size_t)ts * 16 * HH + 32);
            f32x4 s = (f32x4){0.f, 0.f, 0.f, 0.f};
            s = __builtin_amdgcn_mfma_f32_16x16x32_bf16(af0, b0, s, 0, 0, 0);
            s = __builtin_amdgcn_mfma_f32_16x16x32_bf16(af1, b1, s, 0, 0, 0);
            const int d0 = 144 + lg * 4 - ts * 16 - l15;
            #pragma unroll
            for (int r = 0; r < 4; ++r) {
                const int d = d0 + r;
                float sv = s[r] * 0.125f - dec * (float)d - 12.0f;
                float p  = (ts == 9 && d < 0) ? 0.0f : __expf(sv);
                psum[r] += p;
                Pw[(lg * 4 + r) * 168 + ts * 16 + l15] = f2bf(p);
            }
        }
        #pragma unroll
        for (int off = 1; off < 16; off <<= 1)
            #pragma unroll
            for (int r = 0; r < 4; ++r)
                psum[r] += __shfl_xor(psum[r], off, 64);

        asm volatile("s_waitcnt lgkmcnt(0)" ::: "memory");
        __builtin_amdgcn_sched_barrier(0);

        f32x4 oacc[4];
        #pragma unroll
        for (int ht = 0; ht < 4; ++ht) oacc[ht] = (f32x4){0.f, 0.f, 0.f, 0.f};
        const unsigned short* vp = vt + ((size_t)(gb * 64) + l15) * TT + js + lg * 8;

        __builtin_amdgcn_s_setprio(1);
        #pragma unroll
        for (int kt = 0; kt < 5; ++kt) {
            short8 pa = *(const short8*)((const char*)Pw + l15 * 336 + kt * 64 + lg * 16);
            #pragma unroll
            for (int ht = 0; ht < 4; ++ht) {
                short8 bv = *(const short8*)(vp + (size_t)ht * 16 * TT + kt * 32);
                oacc[ht] = __builtin_amdgcn_mfma_f32_16x16x32_bf16(pa, bv, oacc[ht], 0, 0, 0);
            }
        }
        __builtin_amdgcn_s_setprio(0);

        float inv[4];
        #pragma unroll
        for (int r = 0; r < 4; ++r) inv[r] = 1.0f / psum[r];
        float* op = out + (bbase + i0 + lg * 4) * HH + l15;
        #pragma unroll
        for (int ht = 0; ht < 4; ++ht)
            #pragma unroll
            for (int r = 0; r < 4; ++r)
                op[(size_t)r * HH + ht * 16] = oacc[ht][r] * inv[r];
    } else {
        const int NS = (i0 >> 4) + 1;
        const int NK = (NS + 1) >> 1;
        const int dbase = i0 + lg * 4 - l15;
        const unsigned short* kp = kb + (bbase + l15) * HH + lg * 8;

        for (int ts = 0; ts < NS; ++ts) {
            short8 b0 = *(const short8*)(kp);
            short8 b1 = *(const short8*)(kp + 32);
            kp += 16 * HH;
            f32x4 s = (f32x4){0.f, 0.f, 0.f, 0.f};
            s = __builtin_amdgcn_mfma_f32_16x16x32_bf16(af0, b0, s, 0, 0, 0);
            s = __builtin_amdgcn_mfma_f32_16x16x32_bf16(af1, b1, s, 0, 0, 0);
            const int d0 = dbase - ts * 16;
            #pragma unroll
            for (int r = 0; r < 4; ++r) {
                const int d = d0 + r;
                float sv = s[r] * 0.125f - dec * (float)d - 12.0f;
                float p  = (d < 0) ? 0.0f : __expf(sv);
                psum[r] += p;
                Pw[(lg * 4 + r) * 168 + ts * 16 + l15] = f2bf(p);
            }
        }
        if (NS & 1) {
            #pragma unroll
            for (int r = 0; r < 4; ++r)
                Pw[(lg * 4 + r) * 168 + NS * 16 + l15] = 0;
        }
        #pragma unroll
        for (int off = 1; off < 16; off <<= 1)
            #pragma unroll
            for (int r = 0; r < 4; ++r)
                psum[r] += __shfl_xor(psum[r], off, 64);

        asm volatile("s_waitcnt lgkmcnt(0)" ::: "memory");
        __builtin_amdgcn_sched_barrier(0);

        f32x4 oacc[4];
        #pragma unroll
        for (int ht = 0; ht < 4; ++ht) oacc[ht] = (f32x4){0.f, 0.f, 0.f, 0.f};
        const unsigned short* vp = vt + ((size_t)(gb * 64) + l15) * TT + lg * 8;

        for (int kt = 0; kt < NK; ++kt) {
            short8 pa = *(const short8*)((const char*)Pw + l15 * 336 + kt * 64 + lg * 16);
            #pragma unroll
            for (int ht = 0; ht < 4; ++ht) {
                short8 bv = *(const short8*)(vp + (size_t)ht * 16 * TT + kt * 32);
                oacc[ht] = __builtin_amdgcn_mfma_f32_16x16x32_bf16(pa, bv, oacc[ht], 0, 0, 0);
            }
        }

        float inv[4];
        #pragma unroll
        for (int r = 0; r < 4; ++r) inv[r] = 1.0f / psum[r];
        float* op = out + (bbase + i0 + lg * 4) * HH + l15;
        #pragma unroll
        for (int ht = 0; ht < 4; ++ht)
            #pragma unroll
            for (int r = 0; r < 4; ++r)
                op[(size_t)r * HH + ht * 16] = oacc[ht][r] * inv[r];
    }
}

extern "C" void kernel_launch(void* const* d_in, const int* in_sizes, int n_in,
                              void* d_out, int out_size, void* d_ws, size_t ws_size,
                              hipStream_t stream) {
    const float* x     = (const float*)d_in[0];
    const float* Wq    = (const float*)d_in[1];
    const float* Wk    = (const float*)d_in[2];
    const float* Wv    = (const float*)d_in[3];
    const float* decay = (const float*)d_in[4];
    float* out = (float*)d_out;

    unsigned short* qb  = (unsigned short*)d_ws;          // 2 MB
    unsigned short* kb  = qb + (size_t)MM * HH;           // 2 MB
    unsigned short* vt  = kb + (size_t)MM * HH;           // 2 MB (transposed)
    unsigned short* wtb = vt + (size_t)MM * HH;           // 384 KB

    convw_kernel<<<48, 256, 0, stream>>>(Wq, Wk, Wv, wtb);
    gemm_kernel<<<MM / 32, 256, 0, stream>>>(x, wtb, qb, kb, vt);
    attn_kernel<<<MM / 64, 256, 0, stream>>>(qb, kb, vt, decay, out);
}

// Round 10
// 42.794 us; speedup vs baseline: 1.0867x; 1.0867x over previous
//
#include <hip/hip_runtime.h>
#include <math.h>

#define BB 4
#define TT 4096
#define CC 1024
#define HH 64
#define MM (BB*TT)

typedef __attribute__((ext_vector_type(8))) short  short8;
typedef __attribute__((ext_vector_type(4))) short  short4v;
typedef __attribute__((ext_vector_type(4))) float  f32x4;

static __device__ __forceinline__ unsigned short f2bf(float f) {
    union { float f; unsigned u; } v; v.f = f;
    unsigned r = v.u + 0x7FFF + ((v.u >> 16) & 1);
    return (unsigned short)(r >> 16);
}

// 8x fp32 -> 8x bf16 (RNE) via v_cvt_pk_bf16_f32
static __device__ __forceinline__ short8 cvt8(float4 lo, float4 hi) {
    unsigned u0, u1, u2, u3;
    asm("v_cvt_pk_bf16_f32 %0, %1, %2" : "=v"(u0) : "v"(lo.x), "v"(lo.y));
    asm("v_cvt_pk_bf16_f32 %0, %1, %2" : "=v"(u1) : "v"(lo.z), "v"(lo.w));
    asm("v_cvt_pk_bf16_f32 %0, %1, %2" : "=v"(u2) : "v"(hi.x), "v"(hi.y));
    asm("v_cvt_pk_bf16_f32 %0, %1, %2" : "=v"(u3) : "v"(hi.z), "v"(hi.w));
    union { unsigned u[4]; short8 s; } r;
    r.u[0] = u0; r.u[1] = u1; r.u[2] = u2; r.u[3] = u3;
    return r.s;
}

// ---------------- Kernel 0: W -> W^T bf16 (tiny, unchanged) ----------------
__global__ __launch_bounds__(256) void convw_kernel(
        const float* __restrict__ Wq, const float* __restrict__ Wk,
        const float* __restrict__ Wv, unsigned short* __restrict__ wtb) {
    __shared__ unsigned short sW[64][66];
    const int m    = blockIdx.x >> 4;
    const int cblk = blockIdx.x & 15;
    const float* W = (m == 0) ? Wq : (m == 1) ? Wk : Wv;
    const int lane = threadIdx.x & 63;
    const int w    = threadIdx.x >> 6;
    #pragma unroll
    for (int rep = 0; rep < 16; ++rep) {
        const int cl = w * 16 + rep;
        sW[cl][lane] = f2bf(W[(size_t)(cblk * 64 + cl) * HH + lane]);
    }
    __syncthreads();
    #pragma unroll
    for (int rep = 0; rep < 16; ++rep) {
        const int h2 = w * 16 + rep;
        wtb[(size_t)(m * 64 + h2) * CC + cblk * 64 + lane] = sW[lane][h2];
    }
}

// ---------------- Kernel 1: DMA-free MFMA projection ----------------------
// Hypothesis H10: global_load_lds instr-rate (~75cyc/instr/CU) was the wall.
// A (x, HBM): direct global->VGPR frags, depth-3 ring. NO LDS for A.
// B (wtb, L2): global->reg (issued 2 iters early) -> ds_write_b128 (write-late).
// BM=32, BN=192. 256 thr = 4 waves (2 rg x 2 cg of 96). grid = 512.
// Counted vmcnt(10): newest {B(t+2),A(t+3)} stay in flight. Zero DMA instrs.
__global__ __launch_bounds__(256, 3) void gemm_kernel(
        const float* __restrict__ x,
        const unsigned short* __restrict__ wtb,
        unsigned short* __restrict__ qb,
        unsigned short* __restrict__ kb,
        unsigned short* __restrict__ vt) {
    __shared__ unsigned short Bs[192 * 64];   // 24 KB, XOR slot swizzle
    __shared__ float vstage[64][33];          // v epilogue transpose

    const int tid  = threadIdx.x;
    const int lane = tid & 63;
    const int w    = tid >> 6;
    const int l15  = lane & 15;
    const int lg   = lane >> 4;
    const int row0 = blockIdx.x * 32;
    const int rg   = w >> 1;             // row group 0/1
    const int wc   = (w & 1) * 96;       // col group base

    f32x4 acc[6];
    #pragma unroll
    for (int j = 0; j < 6; ++j) acc[j] = (f32x4){0.f, 0.f, 0.f, 0.f};

    // A source: lane's x row, per-step 4 float4 at k = s*64 + {lg*8, +4, +32, +36}
    const float* xrow = x + (size_t)(row0 + rg * 16 + l15) * CC;
    const int lg8 = lg * 8;

    // B staging map (r2-verified): thread covers wtb row r = it*32 + (tid>>3),
    // octet cb = (tid&7)^((tid>>3)&7); LDS byte = it*4096 + tid*16.
    const int tr = tid >> 3;
    const int cb = (tid & 7) ^ (tr & 7);
    const unsigned short* bwp[6];
    #pragma unroll
    for (int it = 0; it < 6; ++it)
        bwp[it] = wtb + (size_t)(it * 32 + tr) * CC + cb * 8;

    float4 araw[3][4];
    short8 breg[2][6];

#define KS(s_) (((s_) < 16 ? (s_) : 15) * 64)
#define LOAD_B(s_, p_) { \
    _Pragma("unroll") \
    for (int it = 0; it < 6; ++it) \
        breg[p_][it] = *(const short8*)(bwp[it] + KS(s_)); }
#define LOAD_A(s_, sl_) { \
    araw[sl_][0] = *(const float4*)(xrow + KS(s_) + lg8); \
    araw[sl_][1] = *(const float4*)(xrow + KS(s_) + lg8 + 4); \
    araw[sl_][2] = *(const float4*)(xrow + KS(s_) + 32 + lg8); \
    araw[sl_][3] = *(const float4*)(xrow + KS(s_) + 36 + lg8); }
#define WRITE_B(p_) { \
    _Pragma("unroll") \
    for (int it = 0; it < 6; ++it) \
        *(short8*)((char*)Bs + it * 4096 + tid * 16) = breg[p_][it]; }
#define FENCE() __builtin_amdgcn_sched_barrier(0x38F)   // pin VMEM order

    // ---- prologue ----
    LOAD_B(0, 0); FENCE();
    LOAD_A(0, 0); FENCE();
    LOAD_A(1, 1); FENCE();
    LOAD_B(1, 1); FENCE();
    LOAD_A(2, 2); FENCE();
    asm volatile("s_waitcnt vmcnt(10)" ::: "memory");   // B0,A0,A1 landed
    WRITE_B(0);
    asm volatile("s_waitcnt lgkmcnt(0)" ::: "memory");
    __builtin_amdgcn_sched_barrier(0);
    __builtin_amdgcn_s_barrier();

    const int swz = (l15 & 7) << 4;

    #pragma unroll
    for (int t = 0; t < 16; ++t) {
        // cvt A(t) (landed; slot freed for A(t+3))
        short8 af0 = cvt8(araw[t % 3][0], araw[t % 3][1]);
        short8 af1 = cvt8(araw[t % 3][2], araw[t % 3][3]);

        LOAD_B(t + 2, t & 1); FENCE();     // into breg[(t+2)&1] == breg[t&1]
        LOAD_A(t + 3, t % 3); FENCE();

        // compute step t from Bs
        const char* Bsc = (const char*)Bs;
        short8 bf[6][2];
        #pragma unroll
        for (int nf = 0; nf < 6; ++nf)
            #pragma unroll
            for (int kh = 0; kh < 2; ++kh) {
                const int n = wc + nf * 16 + l15;
                bf[nf][kh] = *(const short8*)(Bsc + n * 128 + ((kh * 64 + lg * 16) ^ swz));
            }
        #pragma unroll
        for (int kh = 0; kh < 2; ++kh) {
            short8 af = kh ? af1 : af0;
            #pragma unroll
            for (int nf = 0; nf < 6; ++nf)
                acc[nf] = __builtin_amdgcn_mfma_f32_16x16x32_bf16(
                    af, bf[nf][kh], acc[nf], 0, 0, 0);
        }

        // drain through B(t+1)/A(t+2); keep {B(t+2),A(t+3)} in flight
        asm volatile("s_waitcnt vmcnt(10)" ::: "memory");
        asm volatile("s_waitcnt lgkmcnt(0)" ::: "memory");
        __builtin_amdgcn_sched_barrier(0);
        __builtin_amdgcn_s_barrier();      // all waves done reading Bs(t)

        WRITE_B((t + 1) & 1);              // Bs <- B(t+1)
        asm volatile("s_waitcnt lgkmcnt(0)" ::: "memory");
        __builtin_amdgcn_sched_barrier(0);
        __builtin_amdgcn_s_barrier();      // Bs(t+1) visible
    }
#undef KS
#undef LOAD_B
#undef LOAD_A
#undef WRITE_B
#undef FENCE

    // ---- epilogue: q,k direct; v via LDS transpose ----
    const int b = row0 >> 12;
    #pragma unroll
    for (int nf = 0; nf < 6; ++nf) {
        const int ng = wc + nf * 16 + l15;          // output col
        const int mbase = row0 + rg * 16 + lg * 4;  // output row base
        if (ng < 128) {
            unsigned short* dst = ((ng < 64) ? qb : kb);
            const int h = ng & 63;
            #pragma unroll
            for (int r = 0; r < 4; ++r)
                dst[(size_t)(mbase + r) * HH + h] = f2bf(acc[nf][r]);
        } else {
            #pragma unroll
            for (int r = 0; r < 4; ++r)
                vstage[ng - 128][rg * 16 + lg * 4 + r] = acc[nf][r];
        }
    }
    __syncthreads();
    {
        const int h  = tid >> 2;           // 0..63
        const int mq = (tid & 3) * 8;      // 0,8,16,24
        short8 o;
        #pragma unroll
        for (int j = 0; j < 8; ++j)
            o[j] = (short)f2bf(vstage[h][mq + j]);
        *reinterpret_cast<short8*>(
            vt + ((size_t)(b * 64 + h)) * TT + (row0 & (TT - 1)) + mq) = o;
    }
}

// ---------------- Kernel 2: MFMA windowed causal attention ----------------
// (unchanged since round 4)
__global__ __launch_bounds__(256) void attn_kernel(
        const unsigned short* __restrict__ qb,
        const unsigned short* __restrict__ kb,
        const unsigned short* __restrict__ vt,
        const float* __restrict__ decay,
        float* __restrict__ out) {
    __shared__ unsigned short P[4][16 * 168];

    const int lane = threadIdx.x & 63;
    const int w    = threadIdx.x >> 6;
    const int l15  = lane & 15;
    const int lg   = lane >> 4;
    const int qt   = blockIdx.x * 4 + w;
    const int gb   = qt >> 8;
    const int i0   = (qt & 255) << 4;

    const float dec = fabsf(decay[0]);
    const size_t bbase = (size_t)gb * TT;

    short8 af0, af1;
    {
        const unsigned short* qp = qb + (bbase + i0 + l15) * HH + lg * 8;
        af0 = *(const short8*)(qp);
        af1 = *(const short8*)(qp + 32);
    }

    float psum[4] = {0.f, 0.f, 0.f, 0.f};
    unsigned short* Pw = &P[w][0];

    if (i0 >= 144) {
        const int js = i0 - 144;
        const unsigned short* kp = kb + (bbase + js + l15) * HH + lg * 8;
        #pragma unroll
        for (int ts = 0; ts < 10; ++ts) {
            short8 b0 = *(const short8*)(kp + (size_t)ts * 16 * HH);
            short8 b1 = *(const short8*)(kp + (size_t)ts * 16 * HH + 32);
            f32x4 s = (f32x4){0.f, 0.f, 0.f, 0.f};
            s = __builtin_amdgcn_mfma_f32_16x16x32_bf16(af0, b0, s, 0, 0, 0);
            s = __builtin_amdgcn_mfma_f32_16x16x32_bf16(af1, b1, s, 0, 0, 0);
            const int d0 = 144 + lg * 4 - ts * 16 - l15;
            #pragma unroll
            for (int r = 0; r < 4; ++r) {
                const int d = d0 + r;
                float sv = s[r] * 0.125f - dec * (float)d - 12.0f;
                float p  = (ts == 9 && d < 0) ? 0.0f : __expf(sv);
                psum[r] += p;
                Pw[(lg * 4 + r) * 168 + ts * 16 + l15] = f2bf(p);
            }
        }
        #pragma unroll
        for (int off = 1; off < 16; off <<= 1)
            #pragma unroll
            for (int r = 0; r < 4; ++r)
                psum[r] += __shfl_xor(psum[r], off, 64);

        asm volatile("s_waitcnt lgkmcnt(0)" ::: "memory");
        __builtin_amdgcn_sched_barrier(0);

        f32x4 oacc[4];
        #pragma unroll
        for (int ht = 0; ht < 4; ++ht) oacc[ht] = (f32x4){0.f, 0.f, 0.f, 0.f};
        const unsigned short* vp = vt + ((size_t)(gb * 64) + l15) * TT + js + lg * 8;

        __builtin_amdgcn_s_setprio(1);
        #pragma unroll
        for (int kt = 0; kt < 5; ++kt) {
            short8 pa = *(const short8*)((const char*)Pw + l15 * 336 + kt * 64 + lg * 16);
            #pragma unroll
            for (int ht = 0; ht < 4; ++ht) {
                short8 bv = *(const short8*)(vp + (size_t)ht * 16 * TT + kt * 32);
                oacc[ht] = __builtin_amdgcn_mfma_f32_16x16x32_bf16(pa, bv, oacc[ht], 0, 0, 0);
            }
        }
        __builtin_amdgcn_s_setprio(0);

        float inv[4];
        #pragma unroll
        for (int r = 0; r < 4; ++r) inv[r] = 1.0f / psum[r];
        float* op = out + (bbase + i0 + lg * 4) * HH + l15;
        #pragma unroll
        for (int ht = 0; ht < 4; ++ht)
            #pragma unroll
            for (int r = 0; r < 4; ++r)
                op[(size_t)r * HH + ht * 16] = oacc[ht][r] * inv[r];
    } else {
        const int NS = (i0 >> 4) + 1;
        const int NK = (NS + 1) >> 1;
        const int dbase = i0 + lg * 4 - l15;
        const unsigned short* kp = kb + (bbase + l15) * HH + lg * 8;

        for (int ts = 0; ts < NS; ++ts) {
            short8 b0 = *(const short8*)(kp);
            short8 b1 = *(const short8*)(kp + 32);
            kp += 16 * HH;
            f32x4 s = (f32x4){0.f, 0.f, 0.f, 0.f};
            s = __builtin_amdgcn_mfma_f32_16x16x32_bf16(af0, b0, s, 0, 0, 0);
            s = __builtin_amdgcn_mfma_f32_16x16x32_bf16(af1, b1, s, 0, 0, 0);
            const int d0 = dbase - ts * 16;
            #pragma unroll
            for (int r = 0; r < 4; ++r) {
                const int d = d0 + r;
                float sv = s[r] * 0.125f - dec * (float)d - 12.0f;
                float p  = (d < 0) ? 0.0f : __expf(sv);
                psum[r] += p;
                Pw[(lg * 4 + r) * 168 + ts * 16 + l15] = f2bf(p);
            }
        }
        if (NS & 1) {
            #pragma unroll
            for (int r = 0; r < 4; ++r)
                Pw[(lg * 4 + r) * 168 + NS * 16 + l15] = 0;
        }
        #pragma unroll
        for (int off = 1; off < 16; off <<= 1)
            #pragma unroll
            for (int r = 0; r < 4; ++r)
                psum[r] += __shfl_xor(psum[r], off, 64);

        asm volatile("s_waitcnt lgkmcnt(0)" ::: "memory");
        __builtin_amdgcn_sched_barrier(0);

        f32x4 oacc[4];
        #pragma unroll
        for (int ht = 0; ht < 4; ++ht) oacc[ht] = (f32x4){0.f, 0.f, 0.f, 0.f};
        const unsigned short* vp = vt + ((size_t)(gb * 64) + l15) * TT + lg * 8;

        for (int kt = 0; kt < NK; ++kt) {
            short8 pa = *(const short8*)((const char*)Pw + l15 * 336 + kt * 64 + lg * 16);
            #pragma unroll
            for (int ht = 0; ht < 4; ++ht) {
                short8 bv = *(const short8*)(vp + (size_t)ht * 16 * TT + kt * 32);
                oacc[ht] = __builtin_amdgcn_mfma_f32_16x16x32_bf16(pa, bv, oacc[ht], 0, 0, 0);
            }
        }

        float inv[4];
        #pragma unroll
        for (int r = 0; r < 4; ++r) inv[r] = 1.0f / psum[r];
        float* op = out + (bbase + i0 + lg * 4) * HH + l15;
        #pragma unroll
        for (int ht = 0; ht < 4; ++ht)
            #pragma unroll
            for (int r = 0; r < 4; ++r)
                op[(size_t)r * HH + ht * 16] = oacc[ht][r] * inv[r];
    }
}

extern "C" void kernel_launch(void* const* d_in, const int* in_sizes, int n_in,
                              void* d_out, int out_size, void* d_ws, size_t ws_size,
                              hipStream_t stream) {
    const float* x     = (const float*)d_in[0];
    const float* Wq    = (const float*)d_in[1];
    const float* Wk    = (const float*)d_in[2];
    const float* Wv    = (const float*)d_in[3];
    const float* decay = (const float*)d_in[4];
    float* out = (float*)d_out;

    unsigned short* qb  = (unsigned short*)d_ws;          // 2 MB
    unsigned short* kb  = qb + (size_t)MM * HH;           // 2 MB
    unsigned short* vt  = kb + (size_t)MM * HH;           // 2 MB (transposed)
    unsigned short* wtb = vt + (size_t)MM * HH;           // 384 KB

    convw_kernel<<<48, 256, 0, stream>>>(Wq, Wk, Wv, wtb);
    gemm_kernel<<<MM / 32, 256, 0, stream>>>(x, wtb, qb, kb, vt);
    attn_kernel<<<MM / 64, 256, 0, stream>>>(qb, kb, vt, decay, out);
}